// Round 14
// baseline (53.965 us; speedup 1.0000x reference)
//
#include <hip/hip_runtime.h>

#define N_ATOMS 1024
#define N_EDGES 8192
#define NBATCH  256
#define NEG     0.01f

typedef unsigned int u32;
typedef __attribute__((ext_vector_type(2))) float f32x2;
typedef __attribute__((ext_vector_type(4))) float f32x4;
typedef __attribute__((ext_vector_type(8))) _Float16 f16x8;

__device__ __forceinline__ u32 pkrtz(float lo, float hi) {
    u32 r;
    asm("v_cvt_pkrtz_f16_f32 %0, %1, %2" : "=v"(r) : "v"(lo), "v"(hi));
    return r;
}
#define FMIX_LO(a, w, u) \
    asm("v_fma_mix_f32 %0, %1, %2, %0 op_sel_hi:[0,1,0]" : "+v"(a) : "v"(w), "v"(u))
#define FMIX_HI(a, w, u) \
    asm("v_fma_mix_f32 %0, %1, %2, %0 op_sel:[0,1,0] op_sel_hi:[0,1,0]" : "+v"(a) : "v"(w), "v"(u))

// ---------- workspace layout ----------
#define ROWPTR_OFF 0                   // int[1025]
#define COLW_OFF   4352                // int2[E+pad]
#define SELFW_OFF  (4352 + 73728)      // float[1024]
#define PERM_OFF   (SELFW_OFF + 4096)  // int[1024] slot -> atom (degree sorted)
#define W2T_OFF    (PERM_OFF + 4096)   // u32[2048] f16-pair W2^T

// ---------- LDS layout ----------
#define TSTR_B 144                            // tile row stride bytes
#define SM_TILE_BYTES (N_ATOMS * TSTR_B)      // 147456
#define SM_AUX_OFF SM_TILE_BYTES              // aux: cx2 8KB + cz 4KB = 12288
#define SM_TOTAL (SM_TILE_BYTES + 12288)      // 159744

// =====================================================================
// Kernel 1: CSR (dst-grouped, even-padded) + norm weights + degree-
// sorted perm + W2^T f16. 1 block, amortized.
// =====================================================================
__global__ __launch_bounds__(1024) void build_csr(
    const int* __restrict__ ei,
    int*  __restrict__ rowptr,
    int2* __restrict__ colw,
    float* __restrict__ selfw_g,
    int*  __restrict__ perm_g,
    u32*  __restrict__ w2t,
    const float* __restrict__ W2)
{
    __shared__ int   sdeg[N_ATOMS];
    __shared__ int   sstart[N_ATOMS];
    __shared__ float sdinv[N_ATOMS];
    __shared__ int   wtot[16];
    __shared__ int   hist[128];
    const int t = threadIdx.x;
    const int lane = t & 63;
    const int w = t >> 6;
    const int* srcA = ei;
    const int* dstA = ei + N_EDGES;

    sdeg[t] = 0;
    if (t < 128) hist[t] = 0;
    __syncthreads();
    for (int e = t; e < N_EDGES; e += 1024) atomicAdd(&sdeg[dstA[e]], 1);
    __syncthreads();

    const int deg  = sdeg[t];
    const int pdeg = (deg + 1) & ~1;          // even length
    int v = pdeg;
    #pragma unroll
    for (int d = 1; d < 64; d <<= 1) {
        int u = __shfl_up(v, d, 64);
        if (lane >= d) v += u;
    }
    if (lane == 63) wtot[w] = v;
    __syncthreads();
    if (t == 0) {
        int run = 0;
        #pragma unroll
        for (int i = 0; i < 16; ++i) { int c = wtot[i]; wtot[i] = run; run += c; }
    }
    __syncthreads();
    const int start = v - pdeg + wtot[w];
    sstart[t] = start;
    const float dv = rsqrtf((float)deg + 1.0f);
    sdinv[t] = dv;
    rowptr[t] = start;
    if (t == N_ATOMS - 1) rowptr[N_ATOMS] = start + pdeg;
    selfw_g[t] = dv * dv;
    if (deg & 1) colw[start + deg] = make_int2(0, 0);   // zero-weight pad

    // W2^T in f16 pairs
    #pragma unroll
    for (int i = 0; i < 2; ++i) {
        const int idx = t + i * 1024;
        const int c = idx >> 5, kk = idx & 31;
        w2t[c * 32 + kk] = pkrtz(W2[(2 * kk) * 64 + c], W2[(2 * kk + 1) * 64 + c]);
    }

    const int dcl = deg < 127 ? deg : 127;
    atomicAdd(&hist[dcl], 1);
    sdeg[t] = 0;
    __syncthreads();
    if (t == 0) {
        int run = 0;
        for (int i = 0; i < 128; ++i) { int c = hist[i]; hist[i] = run; run += c; }
    }
    __syncthreads();
    const int pos = atomicAdd(&hist[dcl], 1);
    perm_g[pos] = t;
    __syncthreads();

    for (int e = t; e < N_EDGES; e += 1024) {
        const int d = dstA[e];
        const int s = srcA[e];
        const int slot = atomicAdd(&sdeg[d], 1);
        const float wgt = sdinv[s] * sdinv[d];
        colw[sstart[d] + slot] = make_int2(s, __float_as_int(wgt));
    }
}

// 32 FMIX of one half-row set (4 uint4) onto acc[0..31]
#define FMIX_SET(q0, q1, q2, q3, wt)                                  \
    do {                                                              \
        FMIX_LO(acc[0],  wt, (q0).x); FMIX_HI(acc[1],  wt, (q0).x);   \
        FMIX_LO(acc[2],  wt, (q0).y); FMIX_HI(acc[3],  wt, (q0).y);   \
        FMIX_LO(acc[4],  wt, (q0).z); FMIX_HI(acc[5],  wt, (q0).z);   \
        FMIX_LO(acc[6],  wt, (q0).w); FMIX_HI(acc[7],  wt, (q0).w);   \
        FMIX_LO(acc[8],  wt, (q1).x); FMIX_HI(acc[9],  wt, (q1).x);   \
        FMIX_LO(acc[10], wt, (q1).y); FMIX_HI(acc[11], wt, (q1).y);   \
        FMIX_LO(acc[12], wt, (q1).z); FMIX_HI(acc[13], wt, (q1).z);   \
        FMIX_LO(acc[14], wt, (q1).w); FMIX_HI(acc[15], wt, (q1).w);   \
        FMIX_LO(acc[16], wt, (q2).x); FMIX_HI(acc[17], wt, (q2).x);   \
        FMIX_LO(acc[18], wt, (q2).y); FMIX_HI(acc[19], wt, (q2).y);   \
        FMIX_LO(acc[20], wt, (q2).z); FMIX_HI(acc[21], wt, (q2).z);   \
        FMIX_LO(acc[22], wt, (q2).w); FMIX_HI(acc[23], wt, (q2).w);   \
        FMIX_LO(acc[24], wt, (q3).x); FMIX_HI(acc[25], wt, (q3).x);   \
        FMIX_LO(acc[26], wt, (q3).y); FMIX_HI(acc[27], wt, (q3).y);   \
        FMIX_LO(acc[28], wt, (q3).z); FMIX_HI(acc[29], wt, (q3).z);   \
        FMIX_LO(acc[30], wt, (q3).w); FMIX_HI(acc[31], wt, (q3).w);   \
    } while (0)

#define LOAD_SET(q0, q1, q2, q3, rowbase)                 \
    do {                                                  \
        const uint4* _r = (const uint4*)(rowbase);        \
        q0 = _r[0]; q1 = _r[1]; q2 = _r[2]; q3 = _r[3];   \
    } while (0)

// =====================================================================
// Kernel 2: fused GCN x2 + mean-pool + project. 1 block/molecule,
// 1024 threads. Zig-zag conjugate rounds (slot p then 1023-p) balance
// per-thread edge totals in BOTH gather phases. Phase 2 keeps the
// 2-stage LDS pipeline.
// =====================================================================
__global__ __launch_bounds__(1024, 4) void gnn_main(
    const float* __restrict__ x,
    const int*  __restrict__ rowptr,
    const int2* __restrict__ colw,
    const float* __restrict__ selfw_g,
    const int*  __restrict__ perm_g,
    const float* __restrict__ W1, const float* __restrict__ b1,
    const u32*  __restrict__ w2t, const float* __restrict__ b2,
    const float* __restrict__ Wp, const float* __restrict__ bp,
    float* __restrict__ out)
{
    extern __shared__ char smem[];
    float2* cx2 = (float2*)(smem + SM_AUX_OFF);          // [1024] xy
    float*  cz  = (float*)(smem + SM_AUX_OFF + 8192);    // [1024] z
    float*  paux  = (float*)(smem + SM_AUX_OFF);         // aliased post-phase-1
    float*  wpool = paux;                                //   [16][64]
    float*  gvec  = paux + 1024;                         //   [64]
    float*  proj  = paux + 1088;                         //   [4][128]

    const int t = threadIdx.x;
    const int b = blockIdx.x;
    const float* xb = x + (size_t)b * (3 * N_ATOMS);

    const int ho   = (t & 1) * 64;     // half offset in tile row (bytes)
    const int ho32 = (t & 1) * 32;     // half offset in features
    const int pidx = t >> 1;           // pair (atom) index within round

    // ---- phase 0: coords (split 8B + 4B layout) ----
    {
        cx2[t] = make_float2(xb[3 * t], xb[3 * t + 1]);
        cz[t]  = xb[3 * t + 2];
    }
    __syncthreads();

    // ---- phase 1: zig-zag rounds; 2 lanes/atom; lane computes its
    //      32-feature half of GEMM1 and writes a 64B half-row ----
    #pragma unroll
    for (int r = 0; r < 2; ++r) {
        const int slot = r ? (1023 - pidx) : pidx;
        const int atom = perm_g[slot];
        const int s0 = rowptr[atom];
        const int np = (rowptr[atom + 1] - s0) >> 1;
        const float sw = selfw_g[atom];
        const float2 cs = cx2[atom];
        float A0 = sw * cs.x, A1 = sw * cs.y, A2 = sw * cz[atom];
        const int4* colw4 = (const int4*)(colw + s0);
        int4 cur = make_int4(0, 0, 0, 0);
        if (np > 0) cur = colw4[0];
        for (int i = 0; i < np; ++i) {
            const int4 nxt = (i + 1 < np) ? colw4[i + 1] : cur;   // prefetch
            const float2 c0 = cx2[cur.x];          // partner lane: same addr
            const float2 c1 = cx2[cur.z];          //  -> LDS broadcast
            const float z0 = cz[cur.x], z1 = cz[cur.z];
            const float w0 = __int_as_float(cur.y), w1 = __int_as_float(cur.w);
            A0 += w0 * c0.x + w1 * c1.x;
            A1 += w0 * c0.y + w1 * c1.y;
            A2 += w0 * z0 + w1 * z1;
            cur = nxt;
        }
        u32 pw[16];
        #pragma unroll
        for (int p = 0; p < 16; ++p) {
            const int fc = ho32 + 2 * p;
            f32x2 vv = *(const f32x2*)(b1 + fc);
            vv = __builtin_elementwise_fma((f32x2){A0, A0}, *(const f32x2*)(W1 + fc), vv);
            vv = __builtin_elementwise_fma((f32x2){A1, A1}, *(const f32x2*)(W1 + 64 + fc), vv);
            vv = __builtin_elementwise_fma((f32x2){A2, A2}, *(const f32x2*)(W1 + 128 + fc), vv);
            vv.x = fmaxf(vv.x, NEG * vv.x);
            vv.y = fmaxf(vv.y, NEG * vv.y);
            pw[p] = pkrtz(vv.x, vv.y);
        }
        uint4* half = (uint4*)(smem + (size_t)atom * TSTR_B + ho);
        #pragma unroll
        for (int q = 0; q < 4; ++q)
            half[q] = make_uint4(pw[4 * q], pw[4 * q + 1], pw[4 * q + 2], pw[4 * q + 3]);
    }
    __syncthreads();

    // ---- phase 2: gather; 2 lanes/atom, zig-zag rounds;
    //      2-stage LDS pipeline ----
    int atomR[2];
    u32 pr[2][16];

    #pragma unroll
    for (int r = 0; r < 2; ++r) {
        const int slot = r ? (1023 - pidx) : pidx;
        const int atom = perm_g[slot];
        atomR[r] = atom;
        const int s0e = rowptr[atom];
        const int ne  = rowptr[atom + 1] - s0e;          // even
        const float swk = selfw_g[atom];
        const int2* colw2 = (const int2*)(colw + s0e);

        float acc[32];
        #pragma unroll
        for (int f = 0; f < 32; ++f) acc[f] = 0.0f;
        // self term
        {
            uint4 s0q, s1q, s2q, s3q;
            LOAD_SET(s0q, s1q, s2q, s3q, smem + (size_t)atom * TSTR_B + ho);
            FMIX_SET(s0q, s1q, s2q, s3q, swk);
        }
        if (ne > 0) {
            int2 cwA = colw2[0];
            uint4 a0, a1, a2, a3, b0, b1_, b2_, b3;
            LOAD_SET(a0, a1, a2, a3, smem + (size_t)cwA.x * TSTR_B + ho);
            for (int j = 0; j < ne; j += 2) {
                // stage B: read edge j+1 while computing edge j
                const int2 cwB = colw2[j + 1];
                LOAD_SET(b0, b1_, b2_, b3, smem + (size_t)cwB.x * TSTR_B + ho);
                FMIX_SET(a0, a1, a2, a3, __int_as_float(cwA.y));
                // stage A: read edge j+2 while computing edge j+1
                if (j + 2 < ne) {
                    cwA = colw2[j + 2];
                    LOAD_SET(a0, a1, a2, a3, smem + (size_t)cwA.x * TSTR_B + ho);
                }
                FMIX_SET(b0, b1_, b2_, b3, __int_as_float(cwB.y));
            }
        }
        #pragma unroll
        for (int i = 0; i < 16; ++i) pr[r][i] = pkrtz(acc[2 * i], acc[2 * i + 1]);
    }

    // epilogue fragment loads (issued before the barrier)
    const int l15 = t & 15;
    const int lq  = (t & 63) >> 4;
    const int w   = t >> 6;
    f16x8 wf[2][4];
    #pragma unroll
    for (int kt = 0; kt < 2; ++kt)
        #pragma unroll
        for (int ct = 0; ct < 4; ++ct)
            wf[kt][ct] = *(const f16x8*)(w2t + (ct * 16 + l15) * 32 + kt * 16 + lq * 4);
    float bias[4];
    #pragma unroll
    for (int ct = 0; ct < 4; ++ct) bias[ct] = b2[ct * 16 + l15];

    __syncthreads();   // ALL gathers done -> safe to overwrite tile

    // writeback both half-rows
    #pragma unroll
    for (int r = 0; r < 2; ++r) {
        uint4* dst = (uint4*)(smem + (size_t)atomR[r] * TSTR_B + ho);
        dst[0] = make_uint4(pr[r][0],  pr[r][1],  pr[r][2],  pr[r][3]);
        dst[1] = make_uint4(pr[r][4],  pr[r][5],  pr[r][6],  pr[r][7]);
        dst[2] = make_uint4(pr[r][8],  pr[r][9],  pr[r][10], pr[r][11]);
        dst[3] = make_uint4(pr[r][12], pr[r][13], pr[r][14], pr[r][15]);
    }
    __syncthreads();

    // ---- phase 3: GEMM2 via MFMA f16 + bias + leaky + pool ----
    // Wave w's 64 rows: 32 atoms from round 0, 32 from round 1 (via shfl).
    {
        float pool[4] = {0.f, 0.f, 0.f, 0.f};
        #pragma unroll
        for (int rt = 0; rt < 4; ++rt) {
            const int po = (rt & 1) ? (16 + l15) : l15;
            const int arow = (rt < 2) ? __shfl(atomR[0], 2 * po, 64)
                                      : __shfl(atomR[1], 2 * po, 64);
            const char* ab = smem + (size_t)arow * TSTR_B + lq * 16;
            const f16x8 a0 = *(const f16x8*)(ab);
            const f16x8 a1 = *(const f16x8*)(ab + 64);
            #pragma unroll
            for (int ct = 0; ct < 4; ++ct) {
                f32x4 cf = {0.f, 0.f, 0.f, 0.f};
                cf = __builtin_amdgcn_mfma_f32_16x16x32_f16(a0, wf[0][ct], cf, 0, 0, 0);
                cf = __builtin_amdgcn_mfma_f32_16x16x32_f16(a1, wf[1][ct], cf, 0, 0, 0);
                float s = 0.0f;
                #pragma unroll
                for (int rr = 0; rr < 4; ++rr) {
                    const float vv = cf[rr] + bias[ct];
                    s += fmaxf(vv, NEG * vv);
                }
                pool[ct] += s;
            }
        }
        #pragma unroll
        for (int ct = 0; ct < 4; ++ct) {
            pool[ct] += __shfl_xor(pool[ct], 16, 64);
            pool[ct] += __shfl_xor(pool[ct], 32, 64);
        }
        if ((t & 63) < 16) {
            #pragma unroll
            for (int ct = 0; ct < 4; ++ct)
                wpool[w * 64 + ct * 16 + l15] = pool[ct];
        }
    }
    __syncthreads();

    // ---- final pool + project ----
    if (t < 64) {
        float s = 0.0f;
        #pragma unroll
        for (int ww = 0; ww < 16; ++ww) s += wpool[ww * 64 + t];
        gvec[t] = s * (1.0f / 1024.0f);
    }
    __syncthreads();
    if (t < 512) {
        const int col = t & 127, pc = t >> 7;
        float s = 0.0f;
        #pragma unroll
        for (int f = 0; f < 16; ++f)
            s += gvec[pc * 16 + f] * Wp[(pc * 16 + f) * 128 + col];
        proj[pc * 128 + col] = s;
    }
    __syncthreads();
    if (t < 128) {
        float s = bp[t] + proj[t] + proj[128 + t] + proj[256 + t] + proj[384 + t];
        s = fmaxf(s, NEG * s);
        out[(size_t)b * 128 + t] = s;
    }
}

// =====================================================================
extern "C" void kernel_launch(void* const* d_in, const int* in_sizes, int n_in,
                              void* d_out, int out_size, void* d_ws, size_t ws_size,
                              hipStream_t stream) {
    const float* x  = (const float*)d_in[0];
    const int*   ei = (const int*)  d_in[1];
    const float* W1 = (const float*)d_in[2];
    const float* b1 = (const float*)d_in[3];
    const float* W2 = (const float*)d_in[4];
    const float* b2 = (const float*)d_in[5];
    const float* Wp = (const float*)d_in[6];
    const float* bp = (const float*)d_in[7];
    float* out = (float*)d_out;

    char* ws = (char*)d_ws;
    int*   rowptr = (int*)  (ws + ROWPTR_OFF);
    int2*  colw   = (int2*) (ws + COLW_OFF);
    float* selfw  = (float*)(ws + SELFW_OFF);
    int*   perm   = (int*)  (ws + PERM_OFF);
    u32*   w2t    = (u32*)  (ws + W2T_OFF);

    build_csr<<<1, 1024, 0, stream>>>(ei, rowptr, colw, selfw, perm, w2t, W2);

    (void)hipFuncSetAttribute((const void*)gnn_main,
                              hipFuncAttributeMaxDynamicSharedMemorySize, SM_TOTAL);
    gnn_main<<<NBATCH, 1024, SM_TOTAL, stream>>>(
        x, rowptr, colw, selfw, perm, W1, b1, w2t, b2, Wp, bp, out);
}

// Round 15
// 38.070 us; speedup vs baseline: 1.4175x; 1.4175x over previous
//
#include <hip/hip_runtime.h>

#define N_ATOMS 1024
#define N_EDGES 8192
#define NBATCH  256
#define NEG     0.01f

typedef unsigned int u32;
typedef __attribute__((ext_vector_type(2))) float f32x2;
typedef __attribute__((ext_vector_type(4))) float f32x4;
typedef __attribute__((ext_vector_type(8))) _Float16 f16x8;

__device__ __forceinline__ u32 pkrtz(float lo, float hi) {
    u32 r;
    asm("v_cvt_pkrtz_f16_f32 %0, %1, %2" : "=v"(r) : "v"(lo), "v"(hi));
    return r;
}
#define FMIX_LO(a, w, u) \
    asm("v_fma_mix_f32 %0, %1, %2, %0 op_sel_hi:[0,1,0]" : "+v"(a) : "v"(w), "v"(u))
#define FMIX_HI(a, w, u) \
    asm("v_fma_mix_f32 %0, %1, %2, %0 op_sel:[0,1,0] op_sel_hi:[0,1,0]" : "+v"(a) : "v"(w), "v"(u))

// ---------- workspace layout ----------
#define ROWPTR_OFF 0                   // int[1025]
#define COLW_OFF   4352                // int2[E+pad]
#define SELFW_OFF  (4352 + 73728)      // float[1024]
#define PERM_OFF   (SELFW_OFF + 4096)  // int[1024] slot -> atom (degree sorted)
#define W2T_OFF    (PERM_OFF + 4096)   // u32[2048] f16-pair W2^T

// ---------- LDS layout ----------
#define TSTR_B 144                            // tile row stride bytes
#define SM_TILE_BYTES (N_ATOMS * TSTR_B)      // 147456
#define SM_AUX_OFF SM_TILE_BYTES              // aux: cx2 8KB + cz 4KB = 12288
#define SM_TOTAL (SM_TILE_BYTES + 12288)      // 159744

// =====================================================================
// Kernel 1: CSR (dst-grouped, even-padded) + norm weights + degree-
// sorted perm + W2^T f16. 1 block, amortized.
// =====================================================================
__global__ __launch_bounds__(1024) void build_csr(
    const int* __restrict__ ei,
    int*  __restrict__ rowptr,
    int2* __restrict__ colw,
    float* __restrict__ selfw_g,
    int*  __restrict__ perm_g,
    u32*  __restrict__ w2t,
    const float* __restrict__ W2)
{
    __shared__ int   sdeg[N_ATOMS];
    __shared__ int   sstart[N_ATOMS];
    __shared__ float sdinv[N_ATOMS];
    __shared__ int   wtot[16];
    __shared__ int   hist[128];
    const int t = threadIdx.x;
    const int lane = t & 63;
    const int w = t >> 6;
    const int* srcA = ei;
    const int* dstA = ei + N_EDGES;

    sdeg[t] = 0;
    if (t < 128) hist[t] = 0;
    __syncthreads();
    for (int e = t; e < N_EDGES; e += 1024) atomicAdd(&sdeg[dstA[e]], 1);
    __syncthreads();

    const int deg  = sdeg[t];
    const int pdeg = (deg + 1) & ~1;          // even length
    int v = pdeg;
    #pragma unroll
    for (int d = 1; d < 64; d <<= 1) {
        int u = __shfl_up(v, d, 64);
        if (lane >= d) v += u;
    }
    if (lane == 63) wtot[w] = v;
    __syncthreads();
    if (t == 0) {
        int run = 0;
        #pragma unroll
        for (int i = 0; i < 16; ++i) { int c = wtot[i]; wtot[i] = run; run += c; }
    }
    __syncthreads();
    const int start = v - pdeg + wtot[w];
    sstart[t] = start;
    const float dv = rsqrtf((float)deg + 1.0f);
    sdinv[t] = dv;
    rowptr[t] = start;
    if (t == N_ATOMS - 1) rowptr[N_ATOMS] = start + pdeg;
    selfw_g[t] = dv * dv;
    if (deg & 1) colw[start + deg] = make_int2(0, 0);   // zero-weight pad

    // W2^T in f16 pairs
    #pragma unroll
    for (int i = 0; i < 2; ++i) {
        const int idx = t + i * 1024;
        const int c = idx >> 5, kk = idx & 31;
        w2t[c * 32 + kk] = pkrtz(W2[(2 * kk) * 64 + c], W2[(2 * kk + 1) * 64 + c]);
    }

    const int dcl = deg < 127 ? deg : 127;
    atomicAdd(&hist[dcl], 1);
    sdeg[t] = 0;
    __syncthreads();
    if (t == 0) {
        int run = 0;
        for (int i = 0; i < 128; ++i) { int c = hist[i]; hist[i] = run; run += c; }
    }
    __syncthreads();
    const int pos = atomicAdd(&hist[dcl], 1);
    perm_g[pos] = t;
    __syncthreads();

    for (int e = t; e < N_EDGES; e += 1024) {
        const int d = dstA[e];
        const int s = srcA[e];
        const int slot = atomicAdd(&sdeg[d], 1);
        const float wgt = sdinv[s] * sdinv[d];
        colw[sstart[d] + slot] = make_int2(s, __float_as_int(wgt));
    }
}

// 32 FMIX of one half-row set (4 uint4) onto acc[0..31]
#define FMIX_SET(q0, q1, q2, q3, wt)                                  \
    do {                                                              \
        FMIX_LO(acc[0],  wt, (q0).x); FMIX_HI(acc[1],  wt, (q0).x);   \
        FMIX_LO(acc[2],  wt, (q0).y); FMIX_HI(acc[3],  wt, (q0).y);   \
        FMIX_LO(acc[4],  wt, (q0).z); FMIX_HI(acc[5],  wt, (q0).z);   \
        FMIX_LO(acc[6],  wt, (q0).w); FMIX_HI(acc[7],  wt, (q0).w);   \
        FMIX_LO(acc[8],  wt, (q1).x); FMIX_HI(acc[9],  wt, (q1).x);   \
        FMIX_LO(acc[10], wt, (q1).y); FMIX_HI(acc[11], wt, (q1).y);   \
        FMIX_LO(acc[12], wt, (q1).z); FMIX_HI(acc[13], wt, (q1).z);   \
        FMIX_LO(acc[14], wt, (q1).w); FMIX_HI(acc[15], wt, (q1).w);   \
        FMIX_LO(acc[16], wt, (q2).x); FMIX_HI(acc[17], wt, (q2).x);   \
        FMIX_LO(acc[18], wt, (q2).y); FMIX_HI(acc[19], wt, (q2).y);   \
        FMIX_LO(acc[20], wt, (q2).z); FMIX_HI(acc[21], wt, (q2).z);   \
        FMIX_LO(acc[22], wt, (q2).w); FMIX_HI(acc[23], wt, (q2).w);   \
        FMIX_LO(acc[24], wt, (q3).x); FMIX_HI(acc[25], wt, (q3).x);   \
        FMIX_LO(acc[26], wt, (q3).y); FMIX_HI(acc[27], wt, (q3).y);   \
        FMIX_LO(acc[28], wt, (q3).z); FMIX_HI(acc[29], wt, (q3).z);   \
        FMIX_LO(acc[30], wt, (q3).w); FMIX_HI(acc[31], wt, (q3).w);   \
    } while (0)

#define LOAD_SET(q0, q1, q2, q3, rowbase)                 \
    do {                                                  \
        const uint4* _r = (const uint4*)(rowbase);        \
        q0 = _r[0]; q1 = _r[1]; q2 = _r[2]; q3 = _r[3];   \
    } while (0)

// =====================================================================
// Kernel 2: fused GCN x2 + mean-pool + project. 1 block/molecule,
// 1024 threads. R12 structure + hoisted metadata loads + one barrier
// removed (writeback -> MFMA is same-wave visible).
// =====================================================================
__global__ __launch_bounds__(1024, 4) void gnn_main(
    const float* __restrict__ x,
    const int*  __restrict__ rowptr,
    const int2* __restrict__ colw,
    const float* __restrict__ selfw_g,
    const int*  __restrict__ perm_g,
    const float* __restrict__ W1, const float* __restrict__ b1,
    const u32*  __restrict__ w2t, const float* __restrict__ b2,
    const float* __restrict__ Wp, const float* __restrict__ bp,
    float* __restrict__ out)
{
    extern __shared__ char smem[];
    float2* cx2 = (float2*)(smem + SM_AUX_OFF);          // [1024] xy
    float*  cz  = (float*)(smem + SM_AUX_OFF + 8192);    // [1024] z
    float*  paux  = (float*)(smem + SM_AUX_OFF);         // aliased post-phase-1
    float*  wpool = paux;                                //   [16][64]
    float*  gvec  = paux + 1024;                         //   [64]
    float*  proj  = paux + 1088;                         //   [4][128]

    const int t = threadIdx.x;
    const int b = blockIdx.x;
    const float* xb = x + (size_t)b * (3 * N_ATOMS);

    const int ho   = (t & 1) * 64;     // half offset in tile row (bytes)
    const int pidx = t >> 1;           // atom index within phase-2 round

    // ---- hoisted metadata (VMEM in flight under phase 0 + barrier) ----
    const int atom1 = perm_g[t];                       // phase-1 atom
    const int s0p1  = rowptr[atom1];
    const int s1p1  = rowptr[atom1 + 1];
    const float swp1 = selfw_g[atom1];

    int atomR[2], s0R[2], neR[2];
    float swR[2];
    #pragma unroll
    for (int r = 0; r < 2; ++r) {
        const int a = perm_g[r * 512 + pidx];          // phase-2 atoms
        atomR[r] = a;
        s0R[r] = rowptr[a];
        neR[r] = rowptr[a + 1] - s0R[r];               // even
        swR[r] = selfw_g[a];
    }

    // ---- phase 0: coords (split 8B + 4B layout) ----
    {
        cx2[t] = make_float2(xb[3 * t], xb[3 * t + 1]);
        cz[t]  = xb[3 * t + 2];
    }
    __syncthreads();

    // ---- phase 1: aggregate coords, GEMM1 + leaky -> fp16 tile row ----
    {
        const float2 cs = cx2[atom1];
        float A0 = swp1 * cs.x, A1 = swp1 * cs.y, A2 = swp1 * cz[atom1];
        int4 cur = make_int4(0, 0, 0, 0);
        if (s0p1 < s1p1) cur = *(const int4*)(colw + s0p1);
        for (int j = s0p1; j < s1p1; j += 2) {
            const int jn = (j + 2 < s1p1) ? (j + 2) : s0p1;
            const int4 nxt = *(const int4*)(colw + jn);    // prefetch
            const float2 c0 = cx2[cur.x];
            const float2 c1 = cx2[cur.z];
            const float z0 = cz[cur.x], z1 = cz[cur.z];
            const float w0 = __int_as_float(cur.y), w1 = __int_as_float(cur.w);
            A0 += w0 * c0.x + w1 * c1.x;
            A1 += w0 * c0.y + w1 * c1.y;
            A2 += w0 * z0 + w1 * z1;
            cur = nxt;
        }
        u32 pw[32];
        #pragma unroll
        for (int p = 0; p < 32; ++p) {
            f32x2 vv = *(const f32x2*)(b1 + 2 * p);
            vv = __builtin_elementwise_fma((f32x2){A0, A0}, *(const f32x2*)(W1 + 2 * p), vv);
            vv = __builtin_elementwise_fma((f32x2){A1, A1}, *(const f32x2*)(W1 + 64 + 2 * p), vv);
            vv = __builtin_elementwise_fma((f32x2){A2, A2}, *(const f32x2*)(W1 + 128 + 2 * p), vv);
            vv.x = fmaxf(vv.x, NEG * vv.x);
            vv.y = fmaxf(vv.y, NEG * vv.y);
            pw[p] = pkrtz(vv.x, vv.y);
        }
        uint4* trow = (uint4*)(smem + (size_t)atom1 * TSTR_B);
        #pragma unroll
        for (int q = 0; q < 8; ++q)
            trow[q] = make_uint4(pw[4 * q], pw[4 * q + 1], pw[4 * q + 2], pw[4 * q + 3]);
    }
    __syncthreads();

    // ---- phase 2: gather; 2 lanes/atom, 2 rounds; 2-stage LDS pipeline ----
    u32 pr[2][16];
    #pragma unroll
    for (int r = 0; r < 2; ++r) {
        const int atom = atomR[r];
        const int s0e = s0R[r];
        const int ne  = neR[r];
        const float swk = swR[r];
        const int2* colw2 = (const int2*)(colw + s0e);

        float acc[32];
        #pragma unroll
        for (int f = 0; f < 32; ++f) acc[f] = 0.0f;
        // self term
        {
            uint4 s0q, s1q, s2q, s3q;
            LOAD_SET(s0q, s1q, s2q, s3q, smem + (size_t)atom * TSTR_B + ho);
            FMIX_SET(s0q, s1q, s2q, s3q, swk);
        }
        if (ne > 0) {
            int2 cwA = colw2[0];
            uint4 a0, a1, a2, a3, b0, b1_, b2_, b3;
            LOAD_SET(a0, a1, a2, a3, smem + (size_t)cwA.x * TSTR_B + ho);
            for (int j = 0; j < ne; j += 2) {
                // stage B: read edge j+1 while computing edge j
                const int2 cwB = colw2[j + 1];
                LOAD_SET(b0, b1_, b2_, b3, smem + (size_t)cwB.x * TSTR_B + ho);
                FMIX_SET(a0, a1, a2, a3, __int_as_float(cwA.y));
                // stage A: read edge j+2 while computing edge j+1
                if (j + 2 < ne) {
                    cwA = colw2[j + 2];
                    LOAD_SET(a0, a1, a2, a3, smem + (size_t)cwA.x * TSTR_B + ho);
                }
                FMIX_SET(b0, b1_, b2_, b3, __int_as_float(cwB.y));
            }
        }
        #pragma unroll
        for (int i = 0; i < 16; ++i) pr[r][i] = pkrtz(acc[2 * i], acc[2 * i + 1]);
    }

    // epilogue fragment loads (issued before the barrier)
    const int l15 = t & 15;
    const int lq  = (t & 63) >> 4;
    const int w   = t >> 6;
    f16x8 wf[2][4];
    #pragma unroll
    for (int kt = 0; kt < 2; ++kt)
        #pragma unroll
        for (int ct = 0; ct < 4; ++ct)
            wf[kt][ct] = *(const f16x8*)(w2t + (ct * 16 + l15) * 32 + kt * 16 + lq * 4);
    float bias[4];
    #pragma unroll
    for (int ct = 0; ct < 4; ++ct) bias[ct] = b2[ct * 16 + l15];

    __syncthreads();   // ALL gathers done -> safe to overwrite tile

    // writeback both half-rows (own-wave rows; no barrier needed before
    // MFMA because phase 3 reads only rows written by this wave's lanes)
    #pragma unroll
    for (int r = 0; r < 2; ++r) {
        uint4* dst = (uint4*)(smem + (size_t)atomR[r] * TSTR_B + ho);
        dst[0] = make_uint4(pr[r][0],  pr[r][1],  pr[r][2],  pr[r][3]);
        dst[1] = make_uint4(pr[r][4],  pr[r][5],  pr[r][6],  pr[r][7]);
        dst[2] = make_uint4(pr[r][8],  pr[r][9],  pr[r][10], pr[r][11]);
        dst[3] = make_uint4(pr[r][12], pr[r][13], pr[r][14], pr[r][15]);
    }

    // ---- phase 3: GEMM2 via MFMA f16 + bias + leaky + pool ----
    {
        float pool[4] = {0.f, 0.f, 0.f, 0.f};
        #pragma unroll
        for (int rt = 0; rt < 4; ++rt) {
            const int po = (rt & 1) ? (16 + l15) : l15;
            const int arow = (rt < 2) ? __shfl(atomR[0], 2 * po, 64)
                                      : __shfl(atomR[1], 2 * po, 64);
            const char* ab = smem + (size_t)arow * TSTR_B + lq * 16;
            const f16x8 a0 = *(const f16x8*)(ab);
            const f16x8 a1 = *(const f16x8*)(ab + 64);
            #pragma unroll
            for (int ct = 0; ct < 4; ++ct) {
                f32x4 cf = {0.f, 0.f, 0.f, 0.f};
                cf = __builtin_amdgcn_mfma_f32_16x16x32_f16(a0, wf[0][ct], cf, 0, 0, 0);
                cf = __builtin_amdgcn_mfma_f32_16x16x32_f16(a1, wf[1][ct], cf, 0, 0, 0);
                float s = 0.0f;
                #pragma unroll
                for (int rr = 0; rr < 4; ++rr) {
                    const float vv = cf[rr] + bias[ct];
                    s += fmaxf(vv, NEG * vv);
                }
                pool[ct] += s;
            }
        }
        #pragma unroll
        for (int ct = 0; ct < 4; ++ct) {
            pool[ct] += __shfl_xor(pool[ct], 16, 64);
            pool[ct] += __shfl_xor(pool[ct], 32, 64);
        }
        if ((t & 63) < 16) {
            #pragma unroll
            for (int ct = 0; ct < 4; ++ct)
                wpool[w * 64 + ct * 16 + l15] = pool[ct];
        }
    }
    __syncthreads();

    // ---- final pool + project ----
    if (t < 64) {
        float s = 0.0f;
        #pragma unroll
        for (int ww = 0; ww < 16; ++ww) s += wpool[ww * 64 + t];
        gvec[t] = s * (1.0f / 1024.0f);
    }
    __syncthreads();
    if (t < 512) {
        const int col = t & 127, pc = t >> 7;
        float s = 0.0f;
        #pragma unroll
        for (int f = 0; f < 16; ++f)
            s += gvec[pc * 16 + f] * Wp[(pc * 16 + f) * 128 + col];
        proj[pc * 128 + col] = s;
    }
    __syncthreads();
    if (t < 128) {
        float s = bp[t] + proj[t] + proj[128 + t] + proj[256 + t] + proj[384 + t];
        s = fmaxf(s, NEG * s);
        out[(size_t)b * 128 + t] = s;
    }
}

// =====================================================================
extern "C" void kernel_launch(void* const* d_in, const int* in_sizes, int n_in,
                              void* d_out, int out_size, void* d_ws, size_t ws_size,
                              hipStream_t stream) {
    const float* x  = (const float*)d_in[0];
    const int*   ei = (const int*)  d_in[1];
    const float* W1 = (const float*)d_in[2];
    const float* b1 = (const float*)d_in[3];
    const float* W2 = (const float*)d_in[4];
    const float* b2 = (const float*)d_in[5];
    const float* Wp = (const float*)d_in[6];
    const float* bp = (const float*)d_in[7];
    float* out = (float*)d_out;

    char* ws = (char*)d_ws;
    int*   rowptr = (int*)  (ws + ROWPTR_OFF);
    int2*  colw   = (int2*) (ws + COLW_OFF);
    float* selfw  = (float*)(ws + SELFW_OFF);
    int*   perm   = (int*)  (ws + PERM_OFF);
    u32*   w2t    = (u32*)  (ws + W2T_OFF);

    build_csr<<<1, 1024, 0, stream>>>(ei, rowptr, colw, selfw, perm, w2t, W2);

    (void)hipFuncSetAttribute((const void*)gnn_main,
                              hipFuncAttributeMaxDynamicSharedMemorySize, SM_TOTAL);
    gnn_main<<<NBATCH, 1024, SM_TOTAL, stream>>>(
        x, rowptr, colw, selfw, perm, W1, b1, w2t, b2, Wp, bp, out);
}